// Round 6
// baseline (6690.843 us; speedup 1.0000x reference)
//
#include <hip/hip_runtime.h>
#include <hip/hip_fp16.h>
#include <cmath>

#define Bdim 4096
#define Tdim 16
#define Fdim 512
#define Udim 512
#define Mdim 8
#define Kdim 1024   // F + U

typedef __attribute__((ext_vector_type(8))) short bf16x8;
typedef __attribute__((ext_vector_type(4))) float f32x4;
typedef __attribute__((address_space(1))) const void* as1_cvp;
typedef __attribute__((address_space(3))) void* as3_vp;

__device__ __constant__ float c_lntau[8] = {
  0.0f, 1.15129254649702286f, 2.30258509299404572f, 3.45387763949106858f,
  4.60517018598809144f, 5.75646273248511430f, 6.90775527898213716f, 8.05904782547916002f
};
__device__ __constant__ float c_decay[8] = {
  0.96078944f, 0.98743055f, 0.99600799f, 0.99873589f,
  0.99960008f, 0.99987352f, 0.99996000f, 0.99998735f
};

__device__ __forceinline__ unsigned short f2bf(float f) {
  unsigned u = __float_as_uint(f);
  return (unsigned short)((u + 0x7fffu + ((u >> 16) & 1u)) >> 16);
}
__device__ __forceinline__ float bf2f(unsigned short h) {
  return __uint_as_float((unsigned)h << 16);
}
__device__ __forceinline__ void cvt_store8(float4 a, float4 b, short* ph, short* pl) {
  float f[8] = {a.x, a.y, a.z, a.w, b.x, b.y, b.z, b.w};
  bf16x8 hv, lv;
#pragma unroll
  for (int j = 0; j < 8; ++j) {
    unsigned short h = f2bf(f[j]);
    hv[j] = (short)h;
    lv[j] = (short)f2bf(f[j] - bf2f(h));
  }
  *(bf16x8*)ph = hv;
  *(bf16x8*)pl = lv;
}

#define GLOAD16(gp, lp) __builtin_amdgcn_global_load_lds((as1_cvp)(gp), (as3_vp)(lp), 16, 0, 0)

// ---------------------------------------------------------------------------
// W transpose + hi/lo split:  W [1024][ldw] fp32 -> WT_hi/WT_lo [n][1024] bf16
// ---------------------------------------------------------------------------
__global__ __launch_bounds__(256)
void wconv(const float* __restrict__ W, int ldw,
           short* __restrict__ WT_hi, short* __restrict__ WT_lo, int n_off)
{
  __shared__ float tile[64][65];
  const int tid = threadIdx.x;
  const int n0 = blockIdx.x * 64, k0 = blockIdx.y * 64;
#pragma unroll 4
  for (int i = 0; i < 16; ++i) {
    const int kl = i * 4 + (tid >> 6), nl = tid & 63;
    tile[kl][nl] = W[(size_t)(k0 + kl) * ldw + (n0 + nl)];
  }
  __syncthreads();
#pragma unroll 4
  for (int i = 0; i < 16; ++i) {
    const int nl = i * 4 + (tid >> 6), kl = tid & 63;
    const float v = tile[kl][nl];
    const unsigned short h = f2bf(v);
    const size_t di = (size_t)(n_off + n0 + nl) * 1024 + (k0 + kl);
    WT_hi[di] = (short)h;
    WT_lo[di] = (short)f2bf(v - bf2f(h));
  }
}

// split x[:,t,:] into A-buffer cols 0..511
__device__ __forceinline__ void xsplit_row(const float* x, short* Ahw, short* Alw,
                                           int b, int t, int j)
{
  const float* s = x + ((size_t)b * Tdim + t) * Fdim + j * 8;
  const float4 a = *(const float4*)s;
  const float4 c = *(const float4*)(s + 4);
  cvt_store8(a, c, Ahw + (size_t)b * Kdim + j * 8, Alw + (size_t)b * Kdim + j * 8);
}

__global__ __launch_bounds__(64)
void xsplit0(const float* __restrict__ x, short* Ahw, short* Alw)
{
  xsplit_row(x, Ahw, Alw, blockIdx.x, 0, threadIdx.x);
}

// ---------------------------------------------------------------------------
// gemm_rs: [x_t | h] @ [Wr | Ws], 3-term bf16-split MFMA, 128x128 tile, BK=32,
// 4 waves (2x2), wave-tile 64x64. DOUBLE-BUFFERED LDS: stage tile k+1, then
// read frags + MFMA tile k, one barrier per iter (T3 minimum 2-phase).
// ---------------------------------------------------------------------------
__global__ __launch_bounds__(256)
void gemm_rs_mfma(const short* __restrict__ Ahg, const short* __restrict__ Alg,
                  const short* __restrict__ WTh, const short* __restrict__ WTl,
                  const float* __restrict__ br, const float* __restrict__ bs,
                  const float* __restrict__ h_hat, short* __restrict__ Ch,
                  short* __restrict__ Cl, __half* __restrict__ sbuf, int kmax)
{
  __shared__ short Ah[2 * 128 * 32], Al[2 * 128 * 32];
  __shared__ short Bh[2 * 128 * 32], Bl[2 * 128 * 32];
  const int tid = threadIdx.x, lane = tid & 63, wid = tid >> 6;
  const int m0 = blockIdx.y * 128, n0 = blockIdx.x * 128;
  const int wm = wid >> 1, wn = wid & 1;
  const int lrow16 = lane >> 2;        // row within a 16-row chunk
  const int lcb = (lane & 3) * 16;     // byte offset within 64B row slice

  f32x4 acc[4][4];
#pragma unroll
  for (int i = 0; i < 4; ++i)
#pragma unroll
    for (int j = 0; j < 4; ++j) acc[i][j] = 0.0f;

  // stage tile at k0 into buffer `buf`
  auto STAGE = [&](int buf, int k0) {
    const int boff = buf * (128 * 32);           // shorts
#pragma unroll
    for (int i = 0; i < 2; ++i) {
      const int rb = wid * 32 + i * 16;
      const size_t ga = ((size_t)(m0 + rb + lrow16) * Kdim + k0) * 2 + lcb;
      GLOAD16((const char*)Ahg + ga, (char*)(Ah + boff) + rb * 64);
      GLOAD16((const char*)Alg + ga, (char*)(Al + boff) + rb * 64);
      const size_t gw = ((size_t)(n0 + rb + lrow16) * Kdim + k0) * 2 + lcb;
      GLOAD16((const char*)WTh + gw, (char*)(Bh + boff) + rb * 64);
      GLOAD16((const char*)WTl + gw, (char*)(Bl + boff) + rb * 64);
    }
  };

  STAGE(0, 0);
  __syncthreads();                // prologue: buf0 ready
  int cur = 0;

  for (int k0 = 0; k0 < kmax; k0 += 32) {
    if (k0 + 32 < kmax) STAGE(cur ^ 1, k0 + 32);   // prefetch next tile
    const int boff = cur * (128 * 32);
    const int kg = lane >> 4, fr = lane & 15;
    bf16x8 ah[4], al[4], bh[4], bl[4];
#pragma unroll
    for (int mi = 0; mi < 4; ++mi) {
      const int row = wm * 64 + mi * 16 + fr;
      ah[mi] = *(const bf16x8*)&Ah[boff + row * 32 + kg * 8];
      al[mi] = *(const bf16x8*)&Al[boff + row * 32 + kg * 8];
    }
#pragma unroll
    for (int nj = 0; nj < 4; ++nj) {
      const int row = wn * 64 + nj * 16 + fr;
      bh[nj] = *(const bf16x8*)&Bh[boff + row * 32 + kg * 8];
      bl[nj] = *(const bf16x8*)&Bl[boff + row * 32 + kg * 8];
    }
#pragma unroll
    for (int mi = 0; mi < 4; ++mi)
#pragma unroll
      for (int nj = 0; nj < 4; ++nj) {
        acc[mi][nj] = __builtin_amdgcn_mfma_f32_16x16x32_bf16(ah[mi], bh[nj], acc[mi][nj], 0, 0, 0);
        acc[mi][nj] = __builtin_amdgcn_mfma_f32_16x16x32_bf16(ah[mi], bl[nj], acc[mi][nj], 0, 0, 0);
        acc[mi][nj] = __builtin_amdgcn_mfma_f32_16x16x32_bf16(al[mi], bh[nj], acc[mi][nj], 0, 0, 0);
      }
    __syncthreads();   // drains my stage (vmcnt) + everyone's reads of cur
    cur ^= 1;
  }

  // ---- epilogue: softmax over M within 8-lane groups ----
  const bool is_s = (n0 >= Udim * Mdim);
  const float* bias = is_s ? bs : br;
  const int nb = is_s ? n0 - Udim * Mdim : n0;
  const float lnt = c_lntau[lane & 7];
  float bv[4];
#pragma unroll
  for (int nj = 0; nj < 4; ++nj) bv[nj] = bias[nb + wn * 64 + nj * 16 + (lane & 15)];

#pragma unroll
  for (int mi = 0; mi < 4; ++mi)
#pragma unroll
    for (int nj = 0; nj < 4; ++nj)
#pragma unroll
      for (int r = 0; r < 4; ++r) {
        const int brow = m0 + wm * 64 + mi * 16 + (lane >> 4) * 4 + r;
        const int ncol = nb + wn * 64 + nj * 16 + (lane & 15);
        const float v = acc[mi][nj][r] + bv[nj];
        const float d = v - lnt;
        float z = -d * d;
        float zm = z;
        zm = fmaxf(zm, __shfl_xor(zm, 1));
        zm = fmaxf(zm, __shfl_xor(zm, 2));
        zm = fmaxf(zm, __shfl_xor(zm, 4));
        const float e = expf(z - zm);
        float den = e;
        den += __shfl_xor(den, 1);
        den += __shfl_xor(den, 2);
        den += __shfl_xor(den, 4);
        const int u = ncol >> 3;
        if (!is_s) {
          const float hh = h_hat[((size_t)brow * Udim + u) * Mdim + (lane & 7)];
          float num = e * hh;
          num += __shfl_xor(num, 1);
          num += __shfl_xor(num, 2);
          num += __shfl_xor(num, 4);
          if ((lane & 7) == 0) {
            const float c = num / den;
            const unsigned short chh = f2bf(c);
            const size_t ci = (size_t)brow * Udim + u;
            Ch[ci] = (short)chh;
            Cl[ci] = (short)f2bf(c - bf2f(chh));
          }
        } else {
          sbuf[((size_t)brow * Udim + u) * Mdim + (lane & 7)] = __float2half(e / den);
        }
      }
}

// ---------------------------------------------------------------------------
// gemm_q: q = tanh([x_t | ctx] @ Wq + bq); fused h_hat update; writes h as
// bf16 split into A-buffer cols 512..1023. 64x128 tile, BK=32, 4 waves,
// double-buffered (A via global_load_lds; B = Wq fp32 transpose+split in-loop).
// ---------------------------------------------------------------------------
__global__ __launch_bounds__(256)
void gemm_q_mfma(const short* Ahg, const short* Alg,
                 const short* Chg, const short* Clg,
                 const float* __restrict__ Wq, const float* __restrict__ bq,
                 const __half* __restrict__ sbuf, float* __restrict__ h_hat,
                 short* Ahw, short* Alw, int kmax)
{
  __shared__ short Ah[2 * 64 * 32], Al[2 * 64 * 32];
  __shared__ short Bh[2 * 128 * 32], Bl[2 * 128 * 32];
  const int tid = threadIdx.x, lane = tid & 63, wid = tid >> 6;
  const int m0 = blockIdx.y * 64, n0 = blockIdx.x * 128;
  const int wm = wid >> 1, wn = wid & 1;
  const int lrow16 = lane >> 2, lcb = (lane & 3) * 16;
  const int kr = tid & 31, ng = tid >> 5;

  f32x4 acc[2][4];
#pragma unroll
  for (int i = 0; i < 2; ++i)
#pragma unroll
    for (int j = 0; j < 4; ++j) acc[i][j] = 0.0f;

  auto STAGE = [&](int buf, int k0) {
    {   // A: one 16-row chunk per wave
      const int aoff = buf * (64 * 32);
      const int rb = wid * 16;
      if (k0 < Fdim) {
        const size_t ga = ((size_t)(m0 + rb + lrow16) * Kdim + k0) * 2 + lcb;
        GLOAD16((const char*)Ahg + ga, (char*)(Ah + aoff) + rb * 64);
        GLOAD16((const char*)Alg + ga, (char*)(Al + aoff) + rb * 64);
      } else {
        const size_t ga = ((size_t)(m0 + rb + lrow16) * Udim + (k0 - Fdim)) * 2 + lcb;
        GLOAD16((const char*)Chg + ga, (char*)(Ah + aoff) + rb * 64);
        GLOAD16((const char*)Clg + ga, (char*)(Al + aoff) + rb * 64);
      }
    }
    {   // B: fp32 Wq tile -> transpose + split into LDS
      const int boff = buf * (128 * 32);
      const float* wp = Wq + (size_t)(k0 + kr) * Udim + n0 + ng * 16;
      const float4 w0 = *(const float4*)wp,       w1 = *(const float4*)(wp + 4);
      const float4 w2 = *(const float4*)(wp + 8), w3 = *(const float4*)(wp + 12);
      const float wv[16] = {w0.x, w0.y, w0.z, w0.w, w1.x, w1.y, w1.z, w1.w,
                            w2.x, w2.y, w2.z, w2.w, w3.x, w3.y, w3.z, w3.w};
#pragma unroll
      for (int i2 = 0; i2 < 16; ++i2) {
        const unsigned short hh = f2bf(wv[i2]);
        Bh[boff + (ng * 16 + i2) * 32 + kr] = (short)hh;
        Bl[boff + (ng * 16 + i2) * 32 + kr] = (short)f2bf(wv[i2] - bf2f(hh));
      }
    }
  };

  STAGE(0, 0);
  __syncthreads();
  int cur = 0;

  for (int k0 = 0; k0 < kmax; k0 += 32) {
    if (k0 + 32 < kmax) STAGE(cur ^ 1, k0 + 32);
    const int aoff = cur * (64 * 32), boff = cur * (128 * 32);
    const int kg = lane >> 4, fr = lane & 15;
    bf16x8 ah[2], al[2], bh[4], bl[4];
#pragma unroll
    for (int mi = 0; mi < 2; ++mi) {
      const int row = wm * 32 + mi * 16 + fr;
      ah[mi] = *(const bf16x8*)&Ah[aoff + row * 32 + kg * 8];
      al[mi] = *(const bf16x8*)&Al[aoff + row * 32 + kg * 8];
    }
#pragma unroll
    for (int nj = 0; nj < 4; ++nj) {
      const int row = wn * 64 + nj * 16 + fr;
      bh[nj] = *(const bf16x8*)&Bh[boff + row * 32 + kg * 8];
      bl[nj] = *(const bf16x8*)&Bl[boff + row * 32 + kg * 8];
    }
#pragma unroll
    for (int mi = 0; mi < 2; ++mi)
#pragma unroll
      for (int nj = 0; nj < 4; ++nj) {
        acc[mi][nj] = __builtin_amdgcn_mfma_f32_16x16x32_bf16(ah[mi], bh[nj], acc[mi][nj], 0, 0, 0);
        acc[mi][nj] = __builtin_amdgcn_mfma_f32_16x16x32_bf16(ah[mi], bl[nj], acc[mi][nj], 0, 0, 0);
        acc[mi][nj] = __builtin_amdgcn_mfma_f32_16x16x32_bf16(al[mi], bh[nj], acc[mi][nj], 0, 0, 0);
      }
    __syncthreads();
    cur ^= 1;
  }

  // ---- epilogue: tanh + fused h_hat update; h -> bf16 split A-cols ----
  float bv[4];
#pragma unroll
  for (int nj = 0; nj < 4; ++nj) bv[nj] = bq[n0 + wn * 64 + nj * 16 + (lane & 15)];

#pragma unroll
  for (int mi = 0; mi < 2; ++mi)
#pragma unroll
    for (int nj = 0; nj < 4; ++nj)
#pragma unroll
      for (int r = 0; r < 4; ++r) {
        const int b = m0 + wm * 32 + mi * 16 + (lane >> 4) * 4 + r;
        const int u = n0 + wn * 64 + nj * 16 + (lane & 15);
        const float qv = tanhf(acc[mi][nj][r] + bv[nj]);
        const size_t base = ((size_t)b * Udim + u) * Mdim;
        const __half2* sp = (const __half2*)(sbuf + base);
        const __half2 s01 = sp[0], s23 = sp[1], s45 = sp[2], s67 = sp[3];
        const float sv[8] = {__low2float(s01), __high2float(s01), __low2float(s23), __high2float(s23),
                             __low2float(s45), __high2float(s45), __low2float(s67), __high2float(s67)};
        const float4 h0 = *(const float4*)(h_hat + base);
        const float4 h1 = *(const float4*)(h_hat + base + 4);
        float hv[8] = {h0.x, h0.y, h0.z, h0.w, h1.x, h1.y, h1.z, h1.w};
        float sum = 0.f;
#pragma unroll
        for (int m = 0; m < 8; ++m) {
          const float nh = ((1.0f - sv[m]) * hv[m] + sv[m] * qv) * c_decay[m];
          hv[m] = nh;
          sum += nh;
        }
        *(float4*)(h_hat + base)     = make_float4(hv[0], hv[1], hv[2], hv[3]);
        *(float4*)(h_hat + base + 4) = make_float4(hv[4], hv[5], hv[6], hv[7]);
        const unsigned short sh = f2bf(sum);
        Ahw[(size_t)b * Kdim + Fdim + u] = (short)sh;
        Alw[(size_t)b * Kdim + Fdim + u] = (short)f2bf(sum - bf2f(sh));
      }
}

// ---------------------------------------------------------------------------
// out[b,t,:] = h[b,:] @ Wo + bo  (h reconstructed hi+lo); fused x-split for t+1
// ---------------------------------------------------------------------------
__global__ __launch_bounds__(64)
void out_step(const short* Ahg, const short* Alg,
              const float* __restrict__ Wo, const float* __restrict__ bo,
              float* __restrict__ out, const float* __restrict__ x,
              short* Ahw, short* Alw, int t)
{
  const int b = blockIdx.x, lane = threadIdx.x;
  const short* hh = Ahg + (size_t)b * Kdim + Fdim;
  const short* hl = Alg + (size_t)b * Kdim + Fdim;
  float a0 = 0.f, a1 = 0.f, a2 = 0.f;
#pragma unroll
  for (int u0 = 0; u0 < Udim; u0 += 64) {
    const int u = u0 + lane;
    const float hv = bf2f((unsigned short)hh[u]) + bf2f((unsigned short)hl[u]);
    const float* w = Wo + (size_t)u * 3;
    a0 = fmaf(hv, w[0], a0);
    a1 = fmaf(hv, w[1], a1);
    a2 = fmaf(hv, w[2], a2);
  }
#pragma unroll
  for (int off = 32; off; off >>= 1) {
    a0 += __shfl_down(a0, off);
    a1 += __shfl_down(a1, off);
    a2 += __shfl_down(a2, off);
  }
  if (lane == 0) {
    float* o = out + ((size_t)b * Tdim + t) * 3;
    o[0] = a0 + bo[0]; o[1] = a1 + bo[1]; o[2] = a2 + bo[2];
  }
  if (t + 1 < Tdim) xsplit_row(x, Ahw, Alw, b, t + 1, lane);
}

__global__ __launch_bounds__(256)
void zero_kernel(float4* __restrict__ p, size_t n4)
{
  const size_t i = (size_t)blockIdx.x * 256 + threadIdx.x;
  const size_t stride = (size_t)gridDim.x * 256;
  for (size_t j = i; j < n4; j += stride)
    p[j] = make_float4(0.f, 0.f, 0.f, 0.f);
}

extern "C" void kernel_launch(void* const* d_in, const int* in_sizes, int n_in,
                              void* d_out, int out_size, void* d_ws, size_t ws_size,
                              hipStream_t stream)
{
  const float* x  = (const float*)d_in[0];
  const float* Wr = (const float*)d_in[1];
  const float* br = (const float*)d_in[2];
  const float* Wq = (const float*)d_in[3];
  const float* bq = (const float*)d_in[4];
  const float* Ws = (const float*)d_in[5];
  const float* bs = (const float*)d_in[6];
  const float* Wo = (const float*)d_in[7];
  const float* bo = (const float*)d_in[8];
  float* out = (float*)d_out;

  // ws layout (bytes) — totals EXACTLY 159,383,552 (proven available in R3):
  const size_t need = 159383552;
  if (ws_size < need) return;

  char* p = (char*)d_ws;
  short* WTh = (short*)p;  p += 16777216;
  short* WTl = (short*)p;  p += 16777216;
  short* Ahg = (short*)p;  p += 8388608;
  short* Alg = (short*)p;  p += 8388608;
  short* Ch  = (short*)p;  p += 4194304;
  short* Cl  = (short*)p;  p += 4194304;
  float* hhat = (float*)p; p += 67108864;
  __half* sbuf = (__half*)p;

  zero_kernel<<<2048, 256, 0, stream>>>((float4*)hhat, 4194304);
  wconv<<<dim3(64, 16), 256, 0, stream>>>(Wr, 4096, WTh, WTl, 0);
  wconv<<<dim3(64, 16), 256, 0, stream>>>(Ws, 4096, WTh, WTl, 4096);
  xsplit0<<<4096, 64, 0, stream>>>(x, Ahg, Alg);

  for (int t = 0; t < Tdim; ++t) {
    const int kmax = t ? Kdim : Fdim;   // t=0: h=0, ctx=0 exactly -> skip dead half
    gemm_rs_mfma<<<dim3(64, 32), 256, 0, stream>>>(Ahg, Alg, WTh, WTl, br, bs,
                                                   hhat, Ch, Cl, sbuf, kmax);
    gemm_q_mfma<<<dim3(4, 64), 256, 0, stream>>>(Ahg, Alg, Ch, Cl, Wq, bq,
                                                 sbuf, hhat, Ahg, Alg, kmax);
    out_step<<<4096, 64, 0, stream>>>(Ahg, Alg, Wo, bo, out, x, Ahg, Alg, t);
  }
}